// Round 9
// baseline (352.529 us; speedup 1.0000x reference)
//
#include <hip/hip_runtime.h>
#include <hip/hip_bf16.h>
#include <stdint.h>

// GATv2 3-layer network. Round 20:
// GEMM: TK 32->64 (halves barrier/stage iterations per K: L0 16->8,
// L1/L2 4->2; the vmcnt(0)+barrier drain is the documented ~20% stall) +
// swapped-operand MFMA (acc holds C^T fragment) so each thread's 4 acc
// values are 4 CONSECUTIVE C columns -> one 8B packed store, 16 stores vs
// 64 scalar 2B stores. Numerically identical.
// attn (46.4us, VALU 57% + mem 41% ~ saturated): unchanged from R19.
// preproc 8x vectorized (R18), final mean: unchanged.

#define GAT_SLOPE 0.2f
#define ACT_SLOPE 0.01f
#define MAXDEG 64  // Poisson(16): P(deg>64) ~ 1e-18
#define LOG2E 1.44269504088896340736f

typedef _Float16 half8 __attribute__((ext_vector_type(8)));
typedef _Float16 half4 __attribute__((ext_vector_type(4)));
typedef _Float16 v2h __attribute__((ext_vector_type(2)));
typedef float floatx4 __attribute__((ext_vector_type(4)));

// ---------------- fused preprocessing (8-elem vectorized) ----------------
struct TransDesc {
  const float* src;
  _Float16* dst;
  int K, M, off;  // off in ELEMENTS, multiple of 8
  float scale;
};
struct PreArgs {
  TransDesc d[9];
  int wTotal8;  // wTotal / 8
  const float* nf;
  _Float16* A0;
  int aTotal8;  // aTotal / 8
  const int* src;
  const int* dst;
  int* counts;
  int* pcsrc;
  int E;
};

__global__ __launch_bounds__(256) void preproc_kernel(PreArgs pa) {
  int i = blockIdx.x * 256 + threadIdx.x;
  const int total = pa.wTotal8 + pa.aTotal8 + pa.E;
  if (i >= total) return;
  if (i < pa.wTotal8) {
    const int base = i * 8;  // element index
    int q = 0;
#pragma unroll
    for (int j = 1; j < 9; ++j)
      if (base >= pa.d[j].off) q = j;
    const int local = base - pa.d[q].off;  // multiple of 8, within one m-row
    const int K = pa.d[q].K, M = pa.d[q].M;
    const int m = local / K, k0 = local % K;
    const float sc = pa.d[q].scale;
    const float* s = pa.d[q].src;
    half8 o;
#pragma unroll
    for (int q8 = 0; q8 < 8; ++q8)
      o[q8] = (_Float16)(s[(size_t)(k0 + q8) * M + m] * sc);
    *(half8*)(pa.d[q].dst + local) = o;
  } else if (i < pa.wTotal8 + pa.aTotal8) {
    const int j = (i - pa.wTotal8) * 8;
    floatx4 a = *(const floatx4*)(pa.nf + j);
    floatx4 b = *(const floatx4*)(pa.nf + j + 4);
    half8 o = {(_Float16)a[0], (_Float16)a[1], (_Float16)a[2], (_Float16)a[3],
               (_Float16)b[0], (_Float16)b[1], (_Float16)b[2], (_Float16)b[3]};
    *(half8*)(pa.A0 + j) = o;
  } else {
    const int e = i - pa.wTotal8 - pa.aTotal8;
    const int d = pa.dst[e];
    const int pos = atomicAdd(&pa.counts[d], 1);
    if (pos < MAXDEG) pa.pcsrc[(size_t)d * MAXDEG + pos] = pa.src[e];
  }
}

// ---------------- async global -> LDS (16B per lane) ----------------
__device__ __forceinline__ void gload_lds16(const _Float16* g, _Float16* l) {
  __builtin_amdgcn_global_load_lds(
      (__attribute__((address_space(1))) unsigned int*)g,
      (__attribute__((address_space(3))) unsigned int*)l, 16, 0, 0);
}

// ---------------- fp16 MFMA GEMM, dual-B, fp16 output ----------------
#define TM 128
#define TN 128
#define TK 64

__global__ __launch_bounds__(256) void gemm_mfma_dual_kernel(
    const _Float16* __restrict__ A, const _Float16* __restrict__ B0,
    const _Float16* __restrict__ B1, _Float16* __restrict__ C0,
    _Float16* __restrict__ C1, int Nrow, int K, int M, int nStrips,
    int nbxLog2) {
  const int id = blockIdx.x;
  const int xcd = id & 7;
  const int s = id >> 3;
  const int nbx = 1 << nbxLog2;
  const int col = s & (nbx - 1);
  const int chunk = s >> nbxLog2;
  const int strip = chunk * 8 + xcd;
  if (strip >= nStrips) return;

  const int nb = nbx >> 1;
  const bool second = col >= nb;
  const _Float16* B = second ? B1 : B0;
  _Float16* C = second ? C1 : C0;
  const int bn = (second ? col - nb : col) * TN;
  const int bm = strip * TM;

  __shared__ __align__(16) _Float16 As[TM * TK];  // 16 KB
  __shared__ __align__(16) _Float16 Bs[TN * TK];  // 16 KB

  const int tid = threadIdx.x;
  const int w = tid >> 6;
  const int lane = tid & 63;
  const int wr = w >> 1;
  const int wc = w & 1;
  const int quad = lane >> 4;
  const int lr = lane & 15;

  const int lrow8 = lane >> 3;       // 0..7: row within 8-row stripe
  const int loff8 = (lane & 7) * 8;  // 0..56: K-offset (halves)

  floatx4 acc[4][4];
#pragma unroll
  for (int i = 0; i < 4; ++i)
#pragma unroll
    for (int j = 0; j < 4; ++j) acc[i][j] = (floatx4){0.f, 0.f, 0.f, 0.f};

  const int KT = K / TK;
  for (int kt = 0; kt < KT; ++kt) {
    const int k0 = kt * TK;
#pragma unroll
    for (int hh = 0; hh < 4; ++hh) {
      const int r0 = w * 32 + hh * 8;  // wave-uniform 8-row stripe base
      int ga = bm + r0 + lrow8;
      if (ga >= Nrow) ga = Nrow - 1;
      gload_lds16(A + (size_t)ga * K + k0 + loff8, As + r0 * TK);
      gload_lds16(B + (size_t)(bn + r0 + lrow8) * K + k0 + loff8,
                  Bs + r0 * TK);
    }
    __syncthreads();

#pragma unroll
    for (int ks = 0; ks < 2; ++ks) {
      half8 ar[4], br[4];
#pragma unroll
      for (int i = 0; i < 4; ++i) {
        const int row = wr * 64 + i * 16 + lr;
        ar[i] = *(const half8*)(As + row * TK + ks * 32 + quad * 8);
      }
#pragma unroll
      for (int j = 0; j < 4; ++j) {
        const int colr = wc * 64 + j * 16 + lr;
        br[j] = *(const half8*)(Bs + colr * TK + ks * 32 + quad * 8);
      }
      // swapped operands: acc = C^T fragment -> reg r = consecutive C cols
#pragma unroll
      for (int i = 0; i < 4; ++i)
#pragma unroll
        for (int j = 0; j < 4; ++j)
          acc[i][j] = __builtin_amdgcn_mfma_f32_16x16x32_f16(
              br[j], ar[i], acc[i][j], 0, 0, 0);
    }
    __syncthreads();
  }

  // packed epilogue: row = A-row (lr), 4 consecutive cols per acc (quad*4+r)
#pragma unroll
  for (int i = 0; i < 4; ++i) {
    const int row = bm + wr * 64 + i * 16 + lr;
    if (row >= Nrow) continue;
#pragma unroll
    for (int j = 0; j < 4; ++j) {
      const int colc = bn + wc * 64 + j * 16 + quad * 4;
      half4 o = {(_Float16)acc[i][j][0], (_Float16)acc[i][j][1],
                 (_Float16)acc[i][j][2], (_Float16)acc[i][j][3]};
      *(half4*)(C + (size_t)row * M + colc) = o;
    }
  }
}

// ---------------- DPP helpers: add over 16-lane row -------------------
template <int CTRL>
__device__ __forceinline__ float dpp_add(float x) {
  int y = __builtin_amdgcn_update_dpp(0, __builtin_bit_cast(int, x), CTRL,
                                      0xF, 0xF, true);
  return x + __builtin_bit_cast(float, y);
}
__device__ __forceinline__ float row_sum16(float x) {
  x = dpp_add<0x121>(x);  // row_ror:1
  x = dpp_add<0x122>(x);  // row_ror:2
  x = dpp_add<0x124>(x);  // row_ror:4
  x = dpp_add<0x128>(x);  // row_ror:8
  return x;
}

// ---------------- fused per-node GATv2 attention (2 waves / node) ----------
template <int D>
__global__ __launch_bounds__(128) void node_attn_kernel(
    const _Float16* __restrict__ fs, const _Float16* __restrict__ fd,
    const int* __restrict__ counts, const int* __restrict__ pcsrc,
    const _Float16* __restrict__ attnT, const float* __restrict__ bias,
    float* __restrict__ hout, _Float16* __restrict__ oh, int N) {
  constexpr int HD = 4 * D;
  constexpr int R = HD / 64;
  constexpr int R2 = R / 2;
  typedef _Float16 halfR __attribute__((ext_vector_type(R)));
  union Frag {
    halfR v;
    v2h h[R2];
    _Float16 s[R];
  };
  const int v = blockIdx.x;
  if (v >= N) return;
  const int wid = threadIdx.x >> 6;
  const int lane = threadIdx.x & 63;

  const v2h slope2 = {(_Float16)GAT_SLOPE, (_Float16)GAT_SLOPE};

  // prologue loads all issue together
  const int cnt = min(counts[v], MAXDEG);
  int idxReg = pcsrc[(size_t)v * MAXDEG + lane];  // lanes >= cnt never read
  Frag fdv;
  fdv.v = *(const halfR*)(fd + (size_t)v * HD + lane * R);
  Frag arf;
  arf.v = *(const halfR*)(attnT + lane * R);  // pre-scaled by log2e

  float m = -INFINITY, l = 0.f;
  float O[R];
#pragma unroll
  for (int i = 0; i < R; ++i) O[i] = 0.f;

  const int mid = (cnt + 1) >> 1;
  int k = wid ? mid : 0;
  const int ke = wid ? cnt : mid;

  auto loadb = [&](Frag* t, int kk) {
#pragma unroll
    for (int q = 0; q < 4; ++q) {
      const int sidx = __builtin_amdgcn_readlane(idxReg, kk + q);
      t[q].v = *(const halfR*)(fs + (size_t)sidx * HD + lane * R);
    }
  };

  auto compute4 = [&](Frag* t) {
    float p0 = 0.f, p1 = 0.f, p2 = 0.f, p3 = 0.f;
#pragma unroll
    for (int j = 0; j < R2; ++j) {
      v2h x0 = t[0].h[j] + fdv.h[j];
      v2h x1 = t[1].h[j] + fdv.h[j];
      v2h x2 = t[2].h[j] + fdv.h[j];
      v2h x3 = t[3].h[j] + fdv.h[j];
      x0 = __builtin_elementwise_max(x0, x0 * slope2);
      x1 = __builtin_elementwise_max(x1, x1 * slope2);
      x2 = __builtin_elementwise_max(x2, x2 * slope2);
      x3 = __builtin_elementwise_max(x3, x3 * slope2);
      p0 = __builtin_amdgcn_fdot2(arf.h[j], x0, p0, false);
      p1 = __builtin_amdgcn_fdot2(arf.h[j], x1, p1, false);
      p2 = __builtin_amdgcn_fdot2(arf.h[j], x2, p2, false);
      p3 = __builtin_amdgcn_fdot2(arf.h[j], x3, p3, false);
    }
    p0 = row_sum16(p0);
    p1 = row_sum16(p1);
    p2 = row_sum16(p2);
    p3 = row_sum16(p3);
    const float mq = fmaxf(fmaxf(p0, p1), fmaxf(p2, p3));
    const float mnew = fmaxf(m, mq);
    const float sc = __builtin_amdgcn_exp2f(m - mnew);
    const float w0 = __builtin_amdgcn_exp2f(p0 - mnew);
    const float w1 = __builtin_amdgcn_exp2f(p1 - mnew);
    const float w2 = __builtin_amdgcn_exp2f(p2 - mnew);
    const float w3 = __builtin_amdgcn_exp2f(p3 - mnew);
    l = l * sc + (w0 + w1 + w2 + w3);
    // fp16-packed inner accumulation
    const _Float16 h0 = (_Float16)w0, h1 = (_Float16)w1, h2 = (_Float16)w2,
                   h3 = (_Float16)w3;
    const v2h w0v = {h0, h0}, w1v = {h1, h1}, w2v = {h2, h2}, w3v = {h3, h3};
#pragma unroll
    for (int j = 0; j < R2; ++j) {
      v2h s2 = t[0].h[j] * w0v;
      s2 += t[1].h[j] * w1v;
      s2 += t[2].h[j] * w2v;
      s2 += t[3].h[j] * w3v;
      O[2 * j] = fmaf(O[2 * j], sc, (float)s2[0]);
      O[2 * j + 1] = fmaf(O[2 * j + 1], sc, (float)s2[1]);
    }
    m = mnew;
  };

  // double-buffered 4-edge batches (explicit A/B, no runtime-indexed arrays)
  {
    const int nb = (ke - k) >> 2;
    if (nb > 0) {
      Frag tA[4], tB[4];
      loadb(tA, k);
      int bi = 0;
      for (;;) {
        if (bi + 1 < nb) loadb(tB, k + 4);
        compute4(tA);
        k += 4;
        ++bi;
        if (bi == nb) break;
        if (bi + 1 < nb) loadb(tA, k + 4);
        compute4(tB);
        k += 4;
        ++bi;
        if (bi == nb) break;
      }
    }
  }
  // scalar tail (<=3 edges)
  for (; k < ke; ++k) {
    const int sidx = __builtin_amdgcn_readlane(idxReg, k);
    Frag t0;
    t0.v = *(const halfR*)(fs + (size_t)sidx * HD + lane * R);
    float p0 = 0.f;
#pragma unroll
    for (int j = 0; j < R2; ++j) {
      v2h x0 = t0.h[j] + fdv.h[j];
      x0 = __builtin_elementwise_max(x0, x0 * slope2);
      p0 = __builtin_amdgcn_fdot2(arf.h[j], x0, p0, false);
    }
    p0 = row_sum16(p0);
    const float mnew = fmaxf(m, p0);
    const float sc = __builtin_amdgcn_exp2f(m - mnew);
    const float p = __builtin_amdgcn_exp2f(p0 - mnew);
    l = l * sc + p;
#pragma unroll
    for (int i = 0; i < R; ++i) O[i] = fmaf(O[i], sc, p * (float)t0.s[i]);
    m = mnew;
  }

  // flash merge: transposed, conflict-free LDS layout
  __shared__ float sO[64 * R];
  __shared__ float sM[64];
  __shared__ float sL[64];
  if (wid == 1) {
    sM[lane] = m;
    sL[lane] = l;
#pragma unroll
    for (int i = 0; i < R; ++i) sO[i * 64 + lane] = O[i];
  }
  __syncthreads();
  if (wid == 1) return;
  {
    const float m1 = sM[lane];
    const float l1 = sL[lane];
    const float mstar = fmaxf(m, m1);
    const float a0 = (l > 0.f) ? __builtin_amdgcn_exp2f(m - mstar) : 0.f;
    const float a1 = (l1 > 0.f) ? __builtin_amdgcn_exp2f(m1 - mstar) : 0.f;
    l = l * a0 + l1 * a1;
#pragma unroll
    for (int i = 0; i < R; ++i) O[i] = O[i] * a0 + sO[i * 64 + lane] * a1;
  }

  const float inv = (l > 0.f) ? 1.f / l : 0.f;
  float biasv[R];
#pragma unroll
  for (int i = 0; i < R; i += 4) {
    floatx4 b4 = *(const floatx4*)(bias + lane * R + i);
    biasv[i] = b4[0];
    biasv[i + 1] = b4[1];
    biasv[i + 2] = b4[2];
    biasv[i + 3] = b4[3];
  }
#pragma unroll
  for (int i = 0; i < R; ++i) O[i] = O[i] * inv + biasv[i];
#pragma unroll
  for (int i = 0; i < R; ++i) {
    O[i] += __shfl_xor(O[i], 16, 64);
    O[i] += __shfl_xor(O[i], 32, 64);
    float x = O[i] * 0.25f;
    O[i] = x > 0.f ? x : x * ACT_SLOPE;
  }
  if (lane < 16) {
    const size_t base = (size_t)v * D + lane * R;
    if (hout) {
#pragma unroll
      for (int i = 0; i < R; ++i) hout[base + i] = O[i];
    }
    if (oh) {
#pragma unroll
      for (int i = 0; i < R; ++i) oh[base + i] = (_Float16)O[i];
    }
  }
}

// ------------- out[d] = mean_n h[n,d] -------------
__global__ __launch_bounds__(64) void final_mean_kernel(
    const float* __restrict__ h, float* __restrict__ out, int N) {
  const int d = threadIdx.x;
  float acc = 0.f;
  for (int n = blockIdx.x; n < N; n += gridDim.x) acc += h[(size_t)n * 64 + d];
  atomicAdd(&out[d], acc / (float)N);
}

// ------------------------------------------------------------------
extern "C" void kernel_launch(void* const* d_in, const int* in_sizes, int n_in,
                              void* d_out, int out_size, void* d_ws,
                              size_t ws_size, hipStream_t stream) {
  const float* n_feat = (const float*)d_in[0];
  const int* src = (const int*)d_in[1];
  const int* dst = (const int*)d_in[2];
  const float* Wl[3] = {(const float*)d_in[3], (const float*)d_in[7],
                        (const float*)d_in[11]};
  const float* Wr[3] = {(const float*)d_in[4], (const float*)d_in[8],
                        (const float*)d_in[12]};
  const float* attn[3] = {(const float*)d_in[5], (const float*)d_in[9],
                          (const float*)d_in[13]};
  const float* bias[3] = {(const float*)d_in[6], (const float*)d_in[10],
                          (const float*)d_in[14]};

  const int N = in_sizes[0] / 512;  // 20000
  const int E = in_sizes[1];        // 320000
  const int Kdim[3] = {512, 128, 128};
  const int Mdim[3] = {512, 512, 256};
  const int attnLen[3] = {512, 512, 256};

  char* ws = (char*)d_ws;
  size_t o = 0;
  auto alloc = [&](size_t bytes) {
    void* p = ws + o;
    o += (bytes + 15) & ~(size_t)15;
    return p;
  };
  _Float16* fs = (_Float16*)alloc((size_t)N * 512 * 2);
  _Float16* fd = (_Float16*)alloc((size_t)N * 512 * 2);
  _Float16* A0 = (_Float16*)alloc((size_t)N * 512 * 2);
  _Float16* h1 = (_Float16*)alloc((size_t)N * 128 * 2);
  _Float16* h2 = (_Float16*)alloc((size_t)N * 128 * 2);
  float* hfin = (float*)alloc((size_t)N * 64 * 4);
  _Float16 *WlT[3], *WrT[3], *attnT[3];
  for (int L = 0; L < 3; ++L) {
    size_t sz = (size_t)Kdim[L] * Mdim[L] * 2;
    WlT[L] = (_Float16*)alloc(sz);
    WrT[L] = (_Float16*)alloc(sz);
  }
  for (int L = 0; L < 3; ++L) attnT[L] = (_Float16*)alloc(attnLen[L] * 2);
  int* counts = (int*)alloc((size_t)N * 4);
  int* pcsrc = (int*)alloc((size_t)N * MAXDEG * 4);

  // ---- fused preprocessing: transposes + attn cvt + A0 cvt + CSR scatter --
  hipMemsetAsync(counts, 0, (size_t)N * sizeof(int), stream);
  {
    PreArgs pa;
    int off = 0;
    for (int L = 0; L < 3; ++L) {
      pa.d[2 * L] = {Wl[L], WlT[L], Kdim[L], Mdim[L], off, 1.f};
      off += Kdim[L] * Mdim[L];
      pa.d[2 * L + 1] = {Wr[L], WrT[L], Kdim[L], Mdim[L], off, 1.f};
      off += Kdim[L] * Mdim[L];
    }
    for (int L = 0; L < 3; ++L) {
      pa.d[6 + L] = {attn[L], attnT[L], attnLen[L], 1, off, LOG2E};
      off += attnLen[L];
    }
    pa.wTotal8 = off / 8;
    pa.nf = n_feat;
    pa.A0 = A0;
    pa.aTotal8 = N * 512 / 8;
    pa.src = src;
    pa.dst = dst;
    pa.counts = counts;
    pa.pcsrc = pcsrc;
    pa.E = E;
    int total = pa.wTotal8 + pa.aTotal8 + pa.E;
    preproc_kernel<<<(total + 255) / 256, 256, 0, stream>>>(pa);
  }

  const _Float16* Ain[3] = {A0, h1, h2};

  const int nStrips = (N + TM - 1) / TM;   // 157
  const int S8 = ((nStrips + 7) / 8) * 8;  // 160

  for (int L = 0; L < 3; ++L) {
    const int K = Kdim[L], M = Mdim[L];
    const int nbx = 2 * M / TN;  // 8 or 4
    const int nbxLog2 = (nbx == 8) ? 3 : 2;
    gemm_mfma_dual_kernel<<<S8 * nbx, 256, 0, stream>>>(
        Ain[L], WlT[L], WrT[L], fs, fd, N, K, M, nStrips, nbxLog2);
    if (L == 0) {
      node_attn_kernel<128><<<N, 128, 0, stream>>>(fs, fd, counts, pcsrc,
                                                   attnT[L], bias[L], nullptr,
                                                   h1, N);
    } else if (L == 1) {
      node_attn_kernel<128><<<N, 128, 0, stream>>>(fs, fd, counts, pcsrc,
                                                   attnT[L], bias[L], nullptr,
                                                   h2, N);
    } else {
      node_attn_kernel<64><<<N, 128, 0, stream>>>(fs, fd, counts, pcsrc,
                                                  attnT[L], bias[L], hfin,
                                                  nullptr, N);
    }
  }

  hipMemsetAsync(d_out, 0, 64 * sizeof(float), stream);
  final_mean_kernel<<<256, 64, 0, stream>>>(hfin, (float*)d_out, N);
}

// Round 10
// 333.298 us; speedup vs baseline: 1.0577x; 1.0577x over previous
//
#include <hip/hip_runtime.h>
#include <hip/hip_bf16.h>
#include <stdint.h>

// GATv2 3-layer network. Round 21:
// GEMM: R20's TK=64 exposed 7.7M LDS bank conflicts (128B row stride = 32
// banks -> 16-way conflict on fragment reads; MfmaUtil 15.6%). FIX: XOR
// swizzle, both-sides (rule: gload_lds writes linearly -> swizzle the
// per-lane GLOBAL source chunk (chunkL ^ lrow8) and apply the same XOR on
// the ds_read chunk ((ks*4+quad) ^ (lr&7)). Banks: 8 chunks x 4 banks =
// all 32 per 8 lanes, 2 lanes/bank = free. Keeps TK=64 (half the barrier
// drains) + swapped-operand packed half4 epilogue (verified correct, R20).
// attn (46.4us, VALU+mem saturated): unchanged from R19.
// preproc 8x vectorized (R18), final mean: unchanged.

#define GAT_SLOPE 0.2f
#define ACT_SLOPE 0.01f
#define MAXDEG 64  // Poisson(16): P(deg>64) ~ 1e-18
#define LOG2E 1.44269504088896340736f

typedef _Float16 half8 __attribute__((ext_vector_type(8)));
typedef _Float16 half4 __attribute__((ext_vector_type(4)));
typedef _Float16 v2h __attribute__((ext_vector_type(2)));
typedef float floatx4 __attribute__((ext_vector_type(4)));

// ---------------- fused preprocessing (8-elem vectorized) ----------------
struct TransDesc {
  const float* src;
  _Float16* dst;
  int K, M, off;  // off in ELEMENTS, multiple of 8
  float scale;
};
struct PreArgs {
  TransDesc d[9];
  int wTotal8;  // wTotal / 8
  const float* nf;
  _Float16* A0;
  int aTotal8;  // aTotal / 8
  const int* src;
  const int* dst;
  int* counts;
  int* pcsrc;
  int E;
};

__global__ __launch_bounds__(256) void preproc_kernel(PreArgs pa) {
  int i = blockIdx.x * 256 + threadIdx.x;
  const int total = pa.wTotal8 + pa.aTotal8 + pa.E;
  if (i >= total) return;
  if (i < pa.wTotal8) {
    const int base = i * 8;  // element index
    int q = 0;
#pragma unroll
    for (int j = 1; j < 9; ++j)
      if (base >= pa.d[j].off) q = j;
    const int local = base - pa.d[q].off;  // multiple of 8, within one m-row
    const int K = pa.d[q].K, M = pa.d[q].M;
    const int m = local / K, k0 = local % K;
    const float sc = pa.d[q].scale;
    const float* s = pa.d[q].src;
    half8 o;
#pragma unroll
    for (int q8 = 0; q8 < 8; ++q8)
      o[q8] = (_Float16)(s[(size_t)(k0 + q8) * M + m] * sc);
    *(half8*)(pa.d[q].dst + local) = o;
  } else if (i < pa.wTotal8 + pa.aTotal8) {
    const int j = (i - pa.wTotal8) * 8;
    floatx4 a = *(const floatx4*)(pa.nf + j);
    floatx4 b = *(const floatx4*)(pa.nf + j + 4);
    half8 o = {(_Float16)a[0], (_Float16)a[1], (_Float16)a[2], (_Float16)a[3],
               (_Float16)b[0], (_Float16)b[1], (_Float16)b[2], (_Float16)b[3]};
    *(half8*)(pa.A0 + j) = o;
  } else {
    const int e = i - pa.wTotal8 - pa.aTotal8;
    const int d = pa.dst[e];
    const int pos = atomicAdd(&pa.counts[d], 1);
    if (pos < MAXDEG) pa.pcsrc[(size_t)d * MAXDEG + pos] = pa.src[e];
  }
}

// ---------------- async global -> LDS (16B per lane) ----------------
__device__ __forceinline__ void gload_lds16(const _Float16* g, _Float16* l) {
  __builtin_amdgcn_global_load_lds(
      (__attribute__((address_space(1))) unsigned int*)g,
      (__attribute__((address_space(3))) unsigned int*)l, 16, 0, 0);
}

// ---------------- fp16 MFMA GEMM, dual-B, fp16 output ----------------
#define TM 128
#define TN 128
#define TK 64

__global__ __launch_bounds__(256) void gemm_mfma_dual_kernel(
    const _Float16* __restrict__ A, const _Float16* __restrict__ B0,
    const _Float16* __restrict__ B1, _Float16* __restrict__ C0,
    _Float16* __restrict__ C1, int Nrow, int K, int M, int nStrips,
    int nbxLog2) {
  const int id = blockIdx.x;
  const int xcd = id & 7;
  const int s = id >> 3;
  const int nbx = 1 << nbxLog2;
  const int col = s & (nbx - 1);
  const int chunk = s >> nbxLog2;
  const int strip = chunk * 8 + xcd;
  if (strip >= nStrips) return;

  const int nb = nbx >> 1;
  const bool second = col >= nb;
  const _Float16* B = second ? B1 : B0;
  _Float16* C = second ? C1 : C0;
  const int bn = (second ? col - nb : col) * TN;
  const int bm = strip * TM;

  __shared__ __align__(16) _Float16 As[TM * TK];  // 16 KB
  __shared__ __align__(16) _Float16 Bs[TN * TK];  // 16 KB

  const int tid = threadIdx.x;
  const int w = tid >> 6;
  const int lane = tid & 63;
  const int wr = w >> 1;
  const int wc = w & 1;
  const int quad = lane >> 4;
  const int lr = lane & 15;

  const int lrow8 = lane >> 3;   // 0..7: row within 8-row stripe
  const int chunkL = lane & 7;   // 0..7: 16B chunk within 128B row
  // inverse swizzle on the GLOBAL source: LDS[row][c] = G[row][c ^ (row&7)]
  const int loff8s = ((chunkL ^ lrow8) * 8);  // element offset

  floatx4 acc[4][4];
#pragma unroll
  for (int i = 0; i < 4; ++i)
#pragma unroll
    for (int j = 0; j < 4; ++j) acc[i][j] = (floatx4){0.f, 0.f, 0.f, 0.f};

  const int swr = lr & 7;  // read-side XOR key (row&7 == lr&7)

  const int KT = K / TK;
  for (int kt = 0; kt < KT; ++kt) {
    const int k0 = kt * TK;
#pragma unroll
    for (int hh = 0; hh < 4; ++hh) {
      const int r0 = w * 32 + hh * 8;  // wave-uniform 8-row stripe base
      int ga = bm + r0 + lrow8;
      if (ga >= Nrow) ga = Nrow - 1;
      gload_lds16(A + (size_t)ga * K + k0 + loff8s, As + r0 * TK);
      gload_lds16(B + (size_t)(bn + r0 + lrow8) * K + k0 + loff8s,
                  Bs + r0 * TK);
    }
    __syncthreads();

#pragma unroll
    for (int ks = 0; ks < 2; ++ks) {
      half8 ar[4], br[4];
#pragma unroll
      for (int i = 0; i < 4; ++i) {
        const int row = wr * 64 + i * 16 + lr;
        ar[i] = *(const half8*)(As + row * TK + (((ks * 4 + quad) ^ swr) * 8));
      }
#pragma unroll
      for (int j = 0; j < 4; ++j) {
        const int colr = wc * 64 + j * 16 + lr;
        br[j] =
            *(const half8*)(Bs + colr * TK + (((ks * 4 + quad) ^ swr) * 8));
      }
      // swapped operands: acc = C^T fragment -> reg r = consecutive C cols
#pragma unroll
      for (int i = 0; i < 4; ++i)
#pragma unroll
        for (int j = 0; j < 4; ++j)
          acc[i][j] = __builtin_amdgcn_mfma_f32_16x16x32_f16(
              br[j], ar[i], acc[i][j], 0, 0, 0);
    }
    __syncthreads();
  }

  // packed epilogue: row = A-row (lr), 4 consecutive cols per acc (quad*4+r)
#pragma unroll
  for (int i = 0; i < 4; ++i) {
    const int row = bm + wr * 64 + i * 16 + lr;
    if (row >= Nrow) continue;
#pragma unroll
    for (int j = 0; j < 4; ++j) {
      const int colc = bn + wc * 64 + j * 16 + quad * 4;
      half4 o = {(_Float16)acc[i][j][0], (_Float16)acc[i][j][1],
                 (_Float16)acc[i][j][2], (_Float16)acc[i][j][3]};
      *(half4*)(C + (size_t)row * M + colc) = o;
    }
  }
}

// ---------------- DPP helpers: add over 16-lane row -------------------
template <int CTRL>
__device__ __forceinline__ float dpp_add(float x) {
  int y = __builtin_amdgcn_update_dpp(0, __builtin_bit_cast(int, x), CTRL,
                                      0xF, 0xF, true);
  return x + __builtin_bit_cast(float, y);
}
__device__ __forceinline__ float row_sum16(float x) {
  x = dpp_add<0x121>(x);  // row_ror:1
  x = dpp_add<0x122>(x);  // row_ror:2
  x = dpp_add<0x124>(x);  // row_ror:4
  x = dpp_add<0x128>(x);  // row_ror:8
  return x;
}

// ---------------- fused per-node GATv2 attention (2 waves / node) ----------
template <int D>
__global__ __launch_bounds__(128) void node_attn_kernel(
    const _Float16* __restrict__ fs, const _Float16* __restrict__ fd,
    const int* __restrict__ counts, const int* __restrict__ pcsrc,
    const _Float16* __restrict__ attnT, const float* __restrict__ bias,
    float* __restrict__ hout, _Float16* __restrict__ oh, int N) {
  constexpr int HD = 4 * D;
  constexpr int R = HD / 64;
  constexpr int R2 = R / 2;
  typedef _Float16 halfR __attribute__((ext_vector_type(R)));
  union Frag {
    halfR v;
    v2h h[R2];
    _Float16 s[R];
  };
  const int v = blockIdx.x;
  if (v >= N) return;
  const int wid = threadIdx.x >> 6;
  const int lane = threadIdx.x & 63;

  const v2h slope2 = {(_Float16)GAT_SLOPE, (_Float16)GAT_SLOPE};

  // prologue loads all issue together
  const int cnt = min(counts[v], MAXDEG);
  int idxReg = pcsrc[(size_t)v * MAXDEG + lane];  // lanes >= cnt never read
  Frag fdv;
  fdv.v = *(const halfR*)(fd + (size_t)v * HD + lane * R);
  Frag arf;
  arf.v = *(const halfR*)(attnT + lane * R);  // pre-scaled by log2e

  float m = -INFINITY, l = 0.f;
  float O[R];
#pragma unroll
  for (int i = 0; i < R; ++i) O[i] = 0.f;

  const int mid = (cnt + 1) >> 1;
  int k = wid ? mid : 0;
  const int ke = wid ? cnt : mid;

  auto loadb = [&](Frag* t, int kk) {
#pragma unroll
    for (int q = 0; q < 4; ++q) {
      const int sidx = __builtin_amdgcn_readlane(idxReg, kk + q);
      t[q].v = *(const halfR*)(fs + (size_t)sidx * HD + lane * R);
    }
  };

  auto compute4 = [&](Frag* t) {
    float p0 = 0.f, p1 = 0.f, p2 = 0.f, p3 = 0.f;
#pragma unroll
    for (int j = 0; j < R2; ++j) {
      v2h x0 = t[0].h[j] + fdv.h[j];
      v2h x1 = t[1].h[j] + fdv.h[j];
      v2h x2 = t[2].h[j] + fdv.h[j];
      v2h x3 = t[3].h[j] + fdv.h[j];
      x0 = __builtin_elementwise_max(x0, x0 * slope2);
      x1 = __builtin_elementwise_max(x1, x1 * slope2);
      x2 = __builtin_elementwise_max(x2, x2 * slope2);
      x3 = __builtin_elementwise_max(x3, x3 * slope2);
      p0 = __builtin_amdgcn_fdot2(arf.h[j], x0, p0, false);
      p1 = __builtin_amdgcn_fdot2(arf.h[j], x1, p1, false);
      p2 = __builtin_amdgcn_fdot2(arf.h[j], x2, p2, false);
      p3 = __builtin_amdgcn_fdot2(arf.h[j], x3, p3, false);
    }
    p0 = row_sum16(p0);
    p1 = row_sum16(p1);
    p2 = row_sum16(p2);
    p3 = row_sum16(p3);
    const float mq = fmaxf(fmaxf(p0, p1), fmaxf(p2, p3));
    const float mnew = fmaxf(m, mq);
    const float sc = __builtin_amdgcn_exp2f(m - mnew);
    const float w0 = __builtin_amdgcn_exp2f(p0 - mnew);
    const float w1 = __builtin_amdgcn_exp2f(p1 - mnew);
    const float w2 = __builtin_amdgcn_exp2f(p2 - mnew);
    const float w3 = __builtin_amdgcn_exp2f(p3 - mnew);
    l = l * sc + (w0 + w1 + w2 + w3);
    // fp16-packed inner accumulation
    const _Float16 h0 = (_Float16)w0, h1 = (_Float16)w1, h2 = (_Float16)w2,
                   h3 = (_Float16)w3;
    const v2h w0v = {h0, h0}, w1v = {h1, h1}, w2v = {h2, h2}, w3v = {h3, h3};
#pragma unroll
    for (int j = 0; j < R2; ++j) {
      v2h s2 = t[0].h[j] * w0v;
      s2 += t[1].h[j] * w1v;
      s2 += t[2].h[j] * w2v;
      s2 += t[3].h[j] * w3v;
      O[2 * j] = fmaf(O[2 * j], sc, (float)s2[0]);
      O[2 * j + 1] = fmaf(O[2 * j + 1], sc, (float)s2[1]);
    }
    m = mnew;
  };

  // double-buffered 4-edge batches (explicit A/B, no runtime-indexed arrays)
  {
    const int nb = (ke - k) >> 2;
    if (nb > 0) {
      Frag tA[4], tB[4];
      loadb(tA, k);
      int bi = 0;
      for (;;) {
        if (bi + 1 < nb) loadb(tB, k + 4);
        compute4(tA);
        k += 4;
        ++bi;
        if (bi == nb) break;
        if (bi + 1 < nb) loadb(tA, k + 4);
        compute4(tB);
        k += 4;
        ++bi;
        if (bi == nb) break;
      }
    }
  }
  // scalar tail (<=3 edges)
  for (; k < ke; ++k) {
    const int sidx = __builtin_amdgcn_readlane(idxReg, k);
    Frag t0;
    t0.v = *(const halfR*)(fs + (size_t)sidx * HD + lane * R);
    float p0 = 0.f;
#pragma unroll
    for (int j = 0; j < R2; ++j) {
      v2h x0 = t0.h[j] + fdv.h[j];
      x0 = __builtin_elementwise_max(x0, x0 * slope2);
      p0 = __builtin_amdgcn_fdot2(arf.h[j], x0, p0, false);
    }
    p0 = row_sum16(p0);
    const float mnew = fmaxf(m, p0);
    const float sc = __builtin_amdgcn_exp2f(m - mnew);
    const float p = __builtin_amdgcn_exp2f(p0 - mnew);
    l = l * sc + p;
#pragma unroll
    for (int i = 0; i < R; ++i) O[i] = fmaf(O[i], sc, p * (float)t0.s[i]);
    m = mnew;
  }

  // flash merge: transposed, conflict-free LDS layout
  __shared__ float sO[64 * R];
  __shared__ float sM[64];
  __shared__ float sL[64];
  if (wid == 1) {
    sM[lane] = m;
    sL[lane] = l;
#pragma unroll
    for (int i = 0; i < R; ++i) sO[i * 64 + lane] = O[i];
  }
  __syncthreads();
  if (wid == 1) return;
  {
    const float m1 = sM[lane];
    const float l1 = sL[lane];
    const float mstar = fmaxf(m, m1);
    const float a0 = (l > 0.f) ? __builtin_amdgcn_exp2f(m - mstar) : 0.f;
    const float a1 = (l1 > 0.f) ? __builtin_amdgcn_exp2f(m1 - mstar) : 0.f;
    l = l * a0 + l1 * a1;
#pragma unroll
    for (int i = 0; i < R; ++i) O[i] = O[i] * a0 + sO[i * 64 + lane] * a1;
  }

  const float inv = (l > 0.f) ? 1.f / l : 0.f;
  float biasv[R];
#pragma unroll
  for (int i = 0; i < R; i += 4) {
    floatx4 b4 = *(const floatx4*)(bias + lane * R + i);
    biasv[i] = b4[0];
    biasv[i + 1] = b4[1];
    biasv[i + 2] = b4[2];
    biasv[i + 3] = b4[3];
  }
#pragma unroll
  for (int i = 0; i < R; ++i) O[i] = O[i] * inv + biasv[i];
#pragma unroll
  for (int i = 0; i < R; ++i) {
    O[i] += __shfl_xor(O[i], 16, 64);
    O[i] += __shfl_xor(O[i], 32, 64);
    float x = O[i] * 0.25f;
    O[i] = x > 0.f ? x : x * ACT_SLOPE;
  }
  if (lane < 16) {
    const size_t base = (size_t)v * D + lane * R;
    if (hout) {
#pragma unroll
      for (int i = 0; i < R; ++i) hout[base + i] = O[i];
    }
    if (oh) {
#pragma unroll
      for (int i = 0; i < R; ++i) oh[base + i] = (_Float16)O[i];
    }
  }
}

// ------------- out[d] = mean_n h[n,d] -------------
__global__ __launch_bounds__(64) void final_mean_kernel(
    const float* __restrict__ h, float* __restrict__ out, int N) {
  const int d = threadIdx.x;
  float acc = 0.f;
  for (int n = blockIdx.x; n < N; n += gridDim.x) acc += h[(size_t)n * 64 + d];
  atomicAdd(&out[d], acc / (float)N);
}

// ------------------------------------------------------------------
extern "C" void kernel_launch(void* const* d_in, const int* in_sizes, int n_in,
                              void* d_out, int out_size, void* d_ws,
                              size_t ws_size, hipStream_t stream) {
  const float* n_feat = (const float*)d_in[0];
  const int* src = (const int*)d_in[1];
  const int* dst = (const int*)d_in[2];
  const float* Wl[3] = {(const float*)d_in[3], (const float*)d_in[7],
                        (const float*)d_in[11]};
  const float* Wr[3] = {(const float*)d_in[4], (const float*)d_in[8],
                        (const float*)d_in[12]};
  const float* attn[3] = {(const float*)d_in[5], (const float*)d_in[9],
                          (const float*)d_in[13]};
  const float* bias[3] = {(const float*)d_in[6], (const float*)d_in[10],
                          (const float*)d_in[14]};

  const int N = in_sizes[0] / 512;  // 20000
  const int E = in_sizes[1];        // 320000
  const int Kdim[3] = {512, 128, 128};
  const int Mdim[3] = {512, 512, 256};
  const int attnLen[3] = {512, 512, 256};

  char* ws = (char*)d_ws;
  size_t o = 0;
  auto alloc = [&](size_t bytes) {
    void* p = ws + o;
    o += (bytes + 15) & ~(size_t)15;
    return p;
  };
  _Float16* fs = (_Float16*)alloc((size_t)N * 512 * 2);
  _Float16* fd = (_Float16*)alloc((size_t)N * 512 * 2);
  _Float16* A0 = (_Float16*)alloc((size_t)N * 512 * 2);
  _Float16* h1 = (_Float16*)alloc((size_t)N * 128 * 2);
  _Float16* h2 = (_Float16*)alloc((size_t)N * 128 * 2);
  float* hfin = (float*)alloc((size_t)N * 64 * 4);
  _Float16 *WlT[3], *WrT[3], *attnT[3];
  for (int L = 0; L < 3; ++L) {
    size_t sz = (size_t)Kdim[L] * Mdim[L] * 2;
    WlT[L] = (_Float16*)alloc(sz);
    WrT[L] = (_Float16*)alloc(sz);
  }
  for (int L = 0; L < 3; ++L) attnT[L] = (_Float16*)alloc(attnLen[L] * 2);
  int* counts = (int*)alloc((size_t)N * 4);
  int* pcsrc = (int*)alloc((size_t)N * MAXDEG * 4);

  // ---- fused preprocessing: transposes + attn cvt + A0 cvt + CSR scatter --
  hipMemsetAsync(counts, 0, (size_t)N * sizeof(int), stream);
  {
    PreArgs pa;
    int off = 0;
    for (int L = 0; L < 3; ++L) {
      pa.d[2 * L] = {Wl[L], WlT[L], Kdim[L], Mdim[L], off, 1.f};
      off += Kdim[L] * Mdim[L];
      pa.d[2 * L + 1] = {Wr[L], WrT[L], Kdim[L], Mdim[L], off, 1.f};
      off += Kdim[L] * Mdim[L];
    }
    for (int L = 0; L < 3; ++L) {
      pa.d[6 + L] = {attn[L], attnT[L], attnLen[L], 1, off, LOG2E};
      off += attnLen[L];
    }
    pa.wTotal8 = off / 8;
    pa.nf = n_feat;
    pa.A0 = A0;
    pa.aTotal8 = N * 512 / 8;
    pa.src = src;
    pa.dst = dst;
    pa.counts = counts;
    pa.pcsrc = pcsrc;
    pa.E = E;
    int total = pa.wTotal8 + pa.aTotal8 + pa.E;
    preproc_kernel<<<(total + 255) / 256, 256, 0, stream>>>(pa);
  }

  const _Float16* Ain[3] = {A0, h1, h2};

  const int nStrips = (N + TM - 1) / TM;   // 157
  const int S8 = ((nStrips + 7) / 8) * 8;  // 160

  for (int L = 0; L < 3; ++L) {
    const int K = Kdim[L], M = Mdim[L];
    const int nbx = 2 * M / TN;  // 8 or 4
    const int nbxLog2 = (nbx == 8) ? 3 : 2;
    gemm_mfma_dual_kernel<<<S8 * nbx, 256, 0, stream>>>(
        Ain[L], WlT[L], WrT[L], fs, fd, N, K, M, nStrips, nbxLog2);
    if (L == 0) {
      node_attn_kernel<128><<<N, 128, 0, stream>>>(fs, fd, counts, pcsrc,
                                                   attnT[L], bias[L], nullptr,
                                                   h1, N);
    } else if (L == 1) {
      node_attn_kernel<128><<<N, 128, 0, stream>>>(fs, fd, counts, pcsrc,
                                                   attnT[L], bias[L], nullptr,
                                                   h2, N);
    } else {
      node_attn_kernel<64><<<N, 128, 0, stream>>>(fs, fd, counts, pcsrc,
                                                  attnT[L], bias[L], hfin,
                                                  nullptr, N);
    }
  }

  hipMemsetAsync(d_out, 0, 64 * sizeof(float), stream);
  final_mean_kernel<<<256, 64, 0, stream>>>(hfin, (float*)d_out, N);
}